// Round 7
// baseline (1671.810 us; speedup 1.0000x reference)
//
#include <hip/hip_runtime.h>
#include <hip/hip_bf16.h>

#define D_IN   128
#define D_EDGE 32
#define D_OUT  128

// ---------------------------------------------------------------------------
// Kernel 1: fused node transform (64 rows per block).
//   P[n,:]  = bf16( X[n,:] @ Wsrc )   (message precompute, to workspace)
//   Hi[n,:] = X[n,:] @ Wl + bl        (self-loop init of the output, f32)
// ---------------------------------------------------------------------------
__global__ __launch_bounds__(256) void node_transform(
    const float* __restrict__ X,
    const float* __restrict__ Wsrc,
    const float* __restrict__ Wl,
    const float* __restrict__ bl,
    __hip_bfloat16* __restrict__ P,
    float* __restrict__ Hi,
    int N)
{
    __shared__ float Xs[64 * D_IN];  // 32 KB
    const int tid  = threadIdx.x;
    const int row0 = blockIdx.x * 64;
    const int col  = tid & 127;
    const int q    = tid >> 7;

    const int rows = min(64, N - row0);
    if (rows == 64) {
        const float4* X4  = (const float4*)(X + (size_t)row0 * D_IN);
        float4*       Xs4 = (float4*)Xs;
        #pragma unroll
        for (int j = 0; j < 8; ++j) Xs4[tid + j * 256] = X4[tid + j * 256];
    } else {
        for (int i = tid; i < rows * D_IN; i += 256)
            Xs[i] = X[(size_t)row0 * D_IN + i];
        for (int i = rows * D_IN + tid; i < 64 * D_IN; i += 256)
            Xs[i] = 0.f;
    }
    __syncthreads();

    float accP[32], accL[32];
    #pragma unroll
    for (int r = 0; r < 32; ++r) { accP[r] = 0.f; accL[r] = 0.f; }

    for (int k0 = 0; k0 < D_IN; k0 += 4) {
        const float w0 = Wsrc[(k0 + 0) * D_OUT + col];
        const float w1 = Wsrc[(k0 + 1) * D_OUT + col];
        const float w2 = Wsrc[(k0 + 2) * D_OUT + col];
        const float w3 = Wsrc[(k0 + 3) * D_OUT + col];
        const float l0 = Wl[(k0 + 0) * D_OUT + col];
        const float l1 = Wl[(k0 + 1) * D_OUT + col];
        const float l2 = Wl[(k0 + 2) * D_OUT + col];
        const float l3 = Wl[(k0 + 3) * D_OUT + col];
        #pragma unroll
        for (int r = 0; r < 32; ++r) {
            const float4 x = *(const float4*)&Xs[(q * 32 + r) * D_IN + k0];
            accP[r] += x.x * w0 + x.y * w1 + x.z * w2 + x.w * w3;
            accL[r] += x.x * l0 + x.y * l1 + x.z * l2 + x.w * l3;
        }
    }

    const float blc = bl[col];
    #pragma unroll
    for (int r = 0; r < 32; ++r) {
        const int row = row0 + q * 32 + r;
        if (row < N) {
            P [(size_t)row * D_OUT + col] = __float2bfloat16(accP[r]);
            Hi[(size_t)row * D_OUT + col] = accL[r] + blc;
        }
    }
}

// ---------------------------------------------------------------------------
// Counting sort of edges by dst.
// ---------------------------------------------------------------------------
__global__ __launch_bounds__(256) void hist2(
    const int* __restrict__ dst_a, const int* __restrict__ dst_b,
    int* __restrict__ cnt_a, int* __restrict__ cnt_b, int E)
{
    const int i = blockIdx.x * 256 + threadIdx.x;
    const int n = gridDim.x * 256;
    for (int e = i; e < E; e += n) atomicAdd(&cnt_a[dst_a[e]], 1);
    for (int e = i; e < E; e += n) atomicAdd(&cnt_b[dst_b[e]], 1);
}

__global__ __launch_bounds__(256) void scan1(
    const int* __restrict__ cnt, int* __restrict__ offs,
    int* __restrict__ bsum, int N)
{
    __shared__ int s[256];
    const int i = blockIdx.x * 256 + threadIdx.x;
    const int v = (i < N) ? cnt[i] : 0;
    s[threadIdx.x] = v;
    __syncthreads();
    for (int d = 1; d < 256; d <<= 1) {
        const int t = (threadIdx.x >= d) ? s[threadIdx.x - d] : 0;
        __syncthreads();
        s[threadIdx.x] += t;
        __syncthreads();
    }
    const int incl = s[threadIdx.x];
    if (i < N) offs[i] = incl - v;
    if (threadIdx.x == 255) bsum[blockIdx.x] = incl;
}

__global__ __launch_bounds__(512) void scan2(
    int* __restrict__ bsum, int* __restrict__ offs, int N, int nch, int E)
{
    __shared__ int s[512];
    const int v = (threadIdx.x < nch) ? bsum[threadIdx.x] : 0;
    s[threadIdx.x] = v;
    __syncthreads();
    for (int d = 1; d < 512; d <<= 1) {
        const int t = (threadIdx.x >= d) ? s[threadIdx.x - d] : 0;
        __syncthreads();
        s[threadIdx.x] += t;
        __syncthreads();
    }
    if (threadIdx.x < nch) bsum[threadIdx.x] = s[threadIdx.x] - v;
    if (threadIdx.x == 0) offs[N] = E;
}

__global__ __launch_bounds__(256) void scan3(
    int* __restrict__ offs, const int* __restrict__ bsum, int N)
{
    const int i = blockIdx.x * 256 + threadIdx.x;
    if (i < N) offs[i] += bsum[blockIdx.x];
}

// Place (eid, src) pairs into dst-sorted order.
__global__ __launch_bounds__(256) void scatter_sort(
    const int* __restrict__ dst, const int* __restrict__ src,
    const int* __restrict__ offs, int* __restrict__ cnt,
    int2* __restrict__ sorted2, int E)
{
    const int i = blockIdx.x * 256 + threadIdx.x;
    const int n = gridDim.x * 256;
    for (int e = i; e < E; e += n) {
        const int d   = dst[e];
        const int s   = src[e];
        const int old = atomicSub(&cnt[d], 1);
        sorted2[offs[d] + old - 1] = make_int2(e, s);
    }
}

// ---------------------------------------------------------------------------
// Kernel 2: atomic-free aggregation, latency-optimized.
//   H[n,:] += sum_{e in edges(n)} relu(b + P[src[e],:] + Xe[e,:] @ We)
// 256-thread blocks = 2 independent 128-thread node-groups (no LDS, no
// barriers). j-loop unrolled x4 with next-quad prefetch: 4 independent
// random P-gather chains in flight per thread.
// ---------------------------------------------------------------------------
__device__ __forceinline__ float bf16_to_f32(unsigned short u) {
    return __uint_as_float((unsigned int)u << 16);
}

__global__ __launch_bounds__(256) void aggregate(
    const unsigned short* __restrict__ P,  // [Nsrc, D_OUT] bf16 bits
    const float* __restrict__ Xe,          // [E, D_EDGE]
    const float* __restrict__ We,          // [D_EDGE, D_OUT]
    const float* __restrict__ b,           // [D_OUT]
    const int2*  __restrict__ sorted2,     // [E] (eid, src) sorted by dst
    const int*   __restrict__ offs,        // [Ndst+1]
    float*       __restrict__ H,           // [Ndst, D_OUT]
    int N)
{
    const int col = threadIdx.x & 127;
    const int grp = (blockIdx.x << 1) | (threadIdx.x >> 7);
    const int nst = gridDim.x << 1;

    float we[D_EDGE];
    #pragma unroll
    for (int k = 0; k < D_EDGE; ++k) we[k] = We[k * D_OUT + col];
    const float bc = b[col];

    const float4* Xe4 = (const float4*)Xe;

    for (int n = grp; n < N; n += nst) {
        const int off  = offs[n];
        const int deg  = offs[n + 1] - off;
        if (deg == 0) continue;

        float acc = 0.f;
        int j = 0;

        if (deg >= 4) {
            int2 e0 = sorted2[off + 0];
            int2 e1 = sorted2[off + 1];
            int2 e2 = sorted2[off + 2];
            int2 e3 = sorted2[off + 3];
            for (; j + 4 <= deg; ) {
                // issue next quad's index loads early
                const int jn = j + 4;
                int2 f0, f1, f2, f3;
                const bool more = (jn + 4 <= deg);
                if (more) {
                    f0 = sorted2[off + jn + 0];
                    f1 = sorted2[off + jn + 1];
                    f2 = sorted2[off + jn + 2];
                    f3 = sorted2[off + jn + 3];
                }
                // 4 independent P gathers issued together
                const float p0 = bf16_to_f32(P[(size_t)e0.y * D_OUT + col]);
                const float p1 = bf16_to_f32(P[(size_t)e1.y * D_OUT + col]);
                const float p2 = bf16_to_f32(P[(size_t)e2.y * D_OUT + col]);
                const float p3 = bf16_to_f32(P[(size_t)e3.y * D_OUT + col]);
                float v0 = bc + p0, v1 = bc + p1, v2 = bc + p2, v3 = bc + p3;
                const float4* x0 = &Xe4[(size_t)e0.x * 8];
                const float4* x1 = &Xe4[(size_t)e1.x * 8];
                const float4* x2 = &Xe4[(size_t)e2.x * 8];
                const float4* x3 = &Xe4[(size_t)e3.x * 8];
                #pragma unroll
                for (int kk = 0; kk < 8; ++kk) {
                    const float4 a0 = x0[kk], a1 = x1[kk], a2 = x2[kk], a3 = x3[kk];
                    v0 += a0.x * we[4*kk+0] + a0.y * we[4*kk+1] + a0.z * we[4*kk+2] + a0.w * we[4*kk+3];
                    v1 += a1.x * we[4*kk+0] + a1.y * we[4*kk+1] + a1.z * we[4*kk+2] + a1.w * we[4*kk+3];
                    v2 += a2.x * we[4*kk+0] + a2.y * we[4*kk+1] + a2.z * we[4*kk+2] + a2.w * we[4*kk+3];
                    v3 += a3.x * we[4*kk+0] + a3.y * we[4*kk+1] + a3.z * we[4*kk+2] + a3.w * we[4*kk+3];
                }
                acc += fmaxf(v0, 0.f) + fmaxf(v1, 0.f) + fmaxf(v2, 0.f) + fmaxf(v3, 0.f);
                j = jn;
                e0 = f0; e1 = f1; e2 = f2; e3 = f3;
            }
        }
        for (; j < deg; ++j) {
            const int2 e0 = sorted2[off + j];
            float v0 = bc + bf16_to_f32(P[(size_t)e0.y * D_OUT + col]);
            const float4* x0 = &Xe4[(size_t)e0.x * 8];
            #pragma unroll
            for (int kk = 0; kk < 8; ++kk) {
                const float4 a0 = x0[kk];
                v0 += a0.x * we[4*kk+0] + a0.y * we[4*kk+1] + a0.z * we[4*kk+2] + a0.w * we[4*kk+3];
            }
            acc += fmaxf(v0, 0.f);
        }
        H[(size_t)n * D_OUT + col] += acc;
    }
}

// ---------------------------------------------------------------------------
// Fallback: atomic scatter with bf16 P (if sort workspace doesn't fit).
// ---------------------------------------------------------------------------
__global__ __launch_bounds__(256) void edge_scatter(
    const __hip_bfloat16* __restrict__ P, const float* __restrict__ Xe,
    const float* __restrict__ We, const float* __restrict__ b,
    const int* __restrict__ src, const int* __restrict__ dst,
    float* __restrict__ H, int E)
{
    const int tid = threadIdx.x;
    const int col = tid & 127;
    const int sub = tid >> 7;
    float we[D_EDGE];
    #pragma unroll
    for (int k = 0; k < D_EDGE; ++k) we[k] = We[k * D_OUT + col];
    const float bc = b[col];
    const float4* Xe4 = (const float4*)Xe;
    const int slot = blockIdx.x * 2 + sub;
    const int nslots = gridDim.x * 2;
    for (int e = slot; e < E; e += nslots) {
        const int s = src[e];
        const int dt = dst[e];
        float acc = bc + __bfloat162float(P[(size_t)s * D_OUT + col]);
        #pragma unroll
        for (int kk = 0; kk < 8; ++kk) {
            const float4 xv = Xe4[(size_t)e * 8 + kk];
            acc += xv.x * we[4 * kk + 0] + xv.y * we[4 * kk + 1]
                 + xv.z * we[4 * kk + 2] + xv.w * we[4 * kk + 3];
        }
        acc = fmaxf(acc, 0.f);
        unsafeAtomicAdd(&H[(size_t)dt * D_OUT + col], acc);
    }
}

extern "C" void kernel_launch(void* const* d_in, const int* in_sizes, int n_in,
                              void* d_out, int out_size, void* d_ws, size_t ws_size,
                              hipStream_t stream)
{
    const float* X_user    = (const float*)d_in[0];
    const float* X_item    = (const float*)d_in[1];
    const float* Xe_ui     = (const float*)d_in[2];
    const float* Xe_iu     = (const float*)d_in[3];
    const float* W_src_ui  = (const float*)d_in[4];
    const float* W_edge_ui = (const float*)d_in[5];
    const float* b_ui      = (const float*)d_in[6];
    const float* W_src_iu  = (const float*)d_in[7];
    const float* W_edge_iu = (const float*)d_in[8];
    const float* b_iu      = (const float*)d_in[9];
    const float* Wl_user   = (const float*)d_in[10];
    const float* bl_user   = (const float*)d_in[11];
    const float* Wl_item   = (const float*)d_in[12];
    const float* bl_item   = (const float*)d_in[13];
    const int*   src_ui    = (const int*)d_in[14];
    const int*   dst_ui    = (const int*)d_in[15];
    const int*   src_iu    = (const int*)d_in[16];
    const int*   dst_iu    = (const int*)d_in[17];

    const int NU = in_sizes[0] / D_IN;
    const int NI = in_sizes[1] / D_IN;
    const int E  = in_sizes[14];

    float* H_user = (float*)d_out;
    float* H_item = H_user + (size_t)NU * D_OUT;

    // ---- workspace layout ----
    char*  base = (char*)d_ws;
    size_t wo   = 0;
    auto take = [&](size_t bytes) -> void* {
        void* p = base + wo;
        wo = (wo + bytes + 255) & ~(size_t)255;
        return p;
    };
    __hip_bfloat16* P_user = (__hip_bfloat16*)take((size_t)NU * D_OUT * 2);
    __hip_bfloat16* P_item = (__hip_bfloat16*)take((size_t)NI * D_OUT * 2);
    int2* sorted_ui = (int2*)take((size_t)E * 8);
    int2* sorted_iu = (int2*)take((size_t)E * 8);
    int*  offs_i    = (int*)take(((size_t)NI + 1) * 4);  // dst of ui = items
    int*  offs_u    = (int*)take(((size_t)NU + 1) * 4);  // dst of iu = users
    int*  cnt_i     = (int*)take(((size_t)NI + (size_t)NU) * 4);
    int*  cnt_u     = cnt_i + NI;
    const int nch_i = (NI + 255) / 256;
    const int nch_u = (NU + 255) / 256;
    int*  bsum_i    = (int*)take((size_t)nch_i * 4);
    int*  bsum_u    = (int*)take((size_t)nch_u * 4);
    const size_t need_sort = wo;
    const size_t need_P    = ((size_t)NU + (size_t)NI) * D_OUT * 2;

    const int ngrid_u = (NU + 63) / 64;
    const int ngrid_i = (NI + 63) / 64;

    if (ws_size >= need_sort && nch_i <= 512 && nch_u <= 512) {
        // ---- fast path: node GEMMs + counting sort + atomic-free gather ----
        node_transform<<<ngrid_u, 256, 0, stream>>>(
            X_user, W_src_ui, Wl_user, bl_user, P_user, H_user, NU);
        node_transform<<<ngrid_i, 256, 0, stream>>>(
            X_item, W_src_iu, Wl_item, bl_item, P_item, H_item, NI);

        hipMemsetAsync(cnt_i, 0, ((size_t)NI + (size_t)NU) * 4, stream);
        hist2<<<2048, 256, 0, stream>>>(dst_ui, dst_iu, cnt_i, cnt_u, E);

        scan1<<<nch_i, 256, 0, stream>>>(cnt_i, offs_i, bsum_i, NI);
        scan2<<<1, 512, 0, stream>>>(bsum_i, offs_i, NI, nch_i, E);
        scan3<<<nch_i, 256, 0, stream>>>(offs_i, bsum_i, NI);

        scan1<<<nch_u, 256, 0, stream>>>(cnt_u, offs_u, bsum_u, NU);
        scan2<<<1, 512, 0, stream>>>(bsum_u, offs_u, NU, nch_u, E);
        scan3<<<nch_u, 256, 0, stream>>>(offs_u, bsum_u, NU);

        scatter_sort<<<2048, 256, 0, stream>>>(dst_ui, src_ui, offs_i, cnt_i, sorted_ui, E);
        scatter_sort<<<2048, 256, 0, stream>>>(dst_iu, src_iu, offs_u, cnt_u, sorted_iu, E);

        aggregate<<<4096, 256, 0, stream>>>(
            (const unsigned short*)P_user, Xe_ui, W_edge_ui, b_ui, sorted_ui, offs_i, H_item, NI);
        aggregate<<<4096, 256, 0, stream>>>(
            (const unsigned short*)P_item, Xe_iu, W_edge_iu, b_iu, sorted_iu, offs_u, H_user, NU);
    } else {
        // ---- fallback: precomputed bf16 P + atomic scatter ----
        node_transform<<<ngrid_u, 256, 0, stream>>>(
            X_user, W_src_ui, Wl_user, bl_user, P_user, H_user, NU);
        node_transform<<<ngrid_i, 256, 0, stream>>>(
            X_item, W_src_iu, Wl_item, bl_item, P_item, H_item, NI);
        edge_scatter<<<8192, 256, 0, stream>>>(
            P_user, Xe_ui, W_edge_ui, b_ui, src_ui, dst_ui, H_item, E);
        edge_scatter<<<8192, 256, 0, stream>>>(
            P_item, Xe_iu, W_edge_iu, b_iu, src_iu, dst_iu, H_user, E);
    }
}

// Round 10
// 1010.837 us; speedup vs baseline: 1.6539x; 1.6539x over previous
//
#include <hip/hip_runtime.h>
#include <hip/hip_bf16.h>

#define D_IN   128
#define D_EDGE 32
#define D_OUT  128

typedef __attribute__((ext_vector_type(8))) short bf16x8;
typedef __attribute__((ext_vector_type(4))) float f32x4;

__device__ __forceinline__ short f2b(float f) {
    __hip_bfloat16 h = __float2bfloat16(f);
    return *reinterpret_cast<short*>(&h);
}
__device__ __forceinline__ float bf16_to_f32(unsigned short u) {
    return __uint_as_float((unsigned int)u << 16);
}

// ---------------------------------------------------------------------------
// prep: W [128x128] f32 (k-major) -> Wt bf16 [n][k] (transposed), one block/mat
// ---------------------------------------------------------------------------
__global__ __launch_bounds__(256) void prep_wt(
    const float* __restrict__ W, short* __restrict__ Wt)
{
    for (int i = threadIdx.x; i < D_IN * D_OUT; i += 256) {
        const int k = i >> 7, n = i & 127;
        Wt[n * D_IN + k] = f2b(W[i]);
    }
}

// ---------------------------------------------------------------------------
// Kernel 1: MFMA node transform. 256 thr = 4 waves; block = 64 rows; each
// wave owns a 16-row M-tile x full N=128 (8 N-tiles), K=128 in 4 steps of 32.
//   P[n,:]  = bf16( X[n,:] @ Wsrc )     Hi[n,:] = X[n,:] @ Wl + bl
// A frag read from X directly (f32->bf16 cvt); B frags from transposed bf16 Wt
// (L1-resident). No LDS.
// ---------------------------------------------------------------------------
__global__ __launch_bounds__(256) void node_mfma(
    const float* __restrict__ X,
    const short* __restrict__ Wt_s,   // [n][k] bf16
    const short* __restrict__ Wt_l,   // [n][k] bf16
    const float* __restrict__ bl,
    unsigned short* __restrict__ P,   // [N, D_OUT] bf16 bits
    float* __restrict__ Hi,
    int N)
{
    const int wave = threadIdx.x >> 6;
    const int lane = threadIdx.x & 63;
    const int m0   = blockIdx.x * 64 + wave * 16;
    const int arow = m0 + (lane & 15);            // A-frag row
    const int kg   = lane >> 4;                   // k-group 0..3 (8 elems each)
    const int rowc = (arow < N) ? arow : (N - 1); // clamped for loads

    f32x4 accP[8], accL[8];
    #pragma unroll
    for (int nt = 0; nt < 8; ++nt) {
        accP[nt] = (f32x4){0.f, 0.f, 0.f, 0.f};
        accL[nt] = (f32x4){0.f, 0.f, 0.f, 0.f};
    }

    #pragma unroll
    for (int ks = 0; ks < 4; ++ks) {              // k0 = ks*32
        const float4* xp = (const float4*)&X[(size_t)rowc * D_IN + ks * 32 + kg * 8];
        const float4 xa = xp[0], xb = xp[1];
        bf16x8 a;
        a[0] = f2b(xa.x); a[1] = f2b(xa.y); a[2] = f2b(xa.z); a[3] = f2b(xa.w);
        a[4] = f2b(xb.x); a[5] = f2b(xb.y); a[6] = f2b(xb.z); a[7] = f2b(xb.w);
        #pragma unroll
        for (int nt = 0; nt < 8; ++nt) {
            const int n = nt * 16 + (lane & 15);
            const bf16x8 bs = *(const bf16x8*)&Wt_s[(size_t)n * D_IN + ks * 32 + kg * 8];
            const bf16x8 bv = *(const bf16x8*)&Wt_l[(size_t)n * D_IN + ks * 32 + kg * 8];
            accP[nt] = __builtin_amdgcn_mfma_f32_16x16x32_bf16(a, bs, accP[nt], 0, 0, 0);
            accL[nt] = __builtin_amdgcn_mfma_f32_16x16x32_bf16(a, bv, accL[nt], 0, 0, 0);
        }
    }

    // C/D: col = lane&15, row = (lane>>4)*4 + reg
    #pragma unroll
    for (int nt = 0; nt < 8; ++nt) {
        const int col  = nt * 16 + (lane & 15);
        const float bb = bl[col];
        #pragma unroll
        for (int r = 0; r < 4; ++r) {
            const int orow = m0 + (lane >> 4) * 4 + r;
            if (orow < N) {
                P [(size_t)orow * D_OUT + col] = (unsigned short)f2b(accP[nt][r]);
                Hi[(size_t)orow * D_OUT + col] = accL[nt][r] + bb;
            }
        }
    }
}

// ---------------------------------------------------------------------------
// Counting sort of edges by dst.
// ---------------------------------------------------------------------------
__global__ __launch_bounds__(256) void hist2(
    const int* __restrict__ dst_a, const int* __restrict__ dst_b,
    int* __restrict__ cnt_a, int* __restrict__ cnt_b, int E)
{
    const int i = blockIdx.x * 256 + threadIdx.x;
    const int n = gridDim.x * 256;
    for (int e = i; e < E; e += n) atomicAdd(&cnt_a[dst_a[e]], 1);
    for (int e = i; e < E; e += n) atomicAdd(&cnt_b[dst_b[e]], 1);
}

__global__ __launch_bounds__(256) void scan1(
    const int* __restrict__ cnt, int* __restrict__ offs,
    int* __restrict__ bsum, int N)
{
    __shared__ int s[256];
    const int i = blockIdx.x * 256 + threadIdx.x;
    const int v = (i < N) ? cnt[i] : 0;
    s[threadIdx.x] = v;
    __syncthreads();
    for (int d = 1; d < 256; d <<= 1) {
        const int t = (threadIdx.x >= d) ? s[threadIdx.x - d] : 0;
        __syncthreads();
        s[threadIdx.x] += t;
        __syncthreads();
    }
    const int incl = s[threadIdx.x];
    if (i < N) offs[i] = incl - v;
    if (threadIdx.x == 255) bsum[blockIdx.x] = incl;
}

__global__ __launch_bounds__(512) void scan2(
    int* __restrict__ bsum, int* __restrict__ offs, int N, int nch, int E)
{
    __shared__ int s[512];
    const int v = (threadIdx.x < nch) ? bsum[threadIdx.x] : 0;
    s[threadIdx.x] = v;
    __syncthreads();
    for (int d = 1; d < 512; d <<= 1) {
        const int t = (threadIdx.x >= d) ? s[threadIdx.x - d] : 0;
        __syncthreads();
        s[threadIdx.x] += t;
        __syncthreads();
    }
    if (threadIdx.x < nch) bsum[threadIdx.x] = s[threadIdx.x] - v;
    if (threadIdx.x == 0) offs[N] = E;
}

__global__ __launch_bounds__(256) void scan3(
    int* __restrict__ offs, const int* __restrict__ bsum, int N)
{
    const int i = blockIdx.x * 256 + threadIdx.x;
    if (i < N) offs[i] += bsum[blockIdx.x];
}

__global__ __launch_bounds__(256) void scatter_sort(
    const int* __restrict__ dst, const int* __restrict__ src,
    const int* __restrict__ offs, int* __restrict__ cnt,
    int2* __restrict__ sorted2, int E)
{
    const int i = blockIdx.x * 256 + threadIdx.x;
    const int n = gridDim.x * 256;
    for (int e = i; e < E; e += n) {
        const int d   = dst[e];
        const int s   = src[e];
        const int old = atomicSub(&cnt[d], 1);
        sorted2[offs[d] + old - 1] = make_int2(e, s);
    }
}

// ---------------------------------------------------------------------------
// Kernel 2: atomic-free aggregation (round-4 proven structure).
// One 128-thread block per dst node; (eid,src) staged in LDS; unroll-2.
//   H[n,:] += sum_{e in edges(n)} relu(b + P[src[e],:] + Xe[e,:] @ We)
// ---------------------------------------------------------------------------
__global__ __launch_bounds__(128) void aggregate(
    const unsigned short* __restrict__ P,  // [Nsrc, D_OUT] bf16 bits
    const float* __restrict__ Xe,          // [E, D_EDGE]
    const float* __restrict__ We,          // [D_EDGE, D_OUT]
    const float* __restrict__ b,           // [D_OUT]
    const int2*  __restrict__ sorted2,     // [E] (eid, src) sorted by dst
    const int*   __restrict__ offs,        // [Ndst+1]
    float*       __restrict__ H,           // [Ndst, D_OUT]
    int N)
{
    const int n   = blockIdx.x;
    const int off = offs[n];
    const int deg = offs[n + 1] - off;
    if (deg == 0) return;

    const int col = threadIdx.x;
    float we[D_EDGE];
    #pragma unroll
    for (int k = 0; k < D_EDGE; ++k) we[k] = We[k * D_OUT + col];
    const float bc = b[col];

    __shared__ int2 es[128];
    const float4* Xe4 = (const float4*)Xe;

    float acc = 0.f;
    for (int base = 0; base < deg; base += 128) {
        const int m = min(128, deg - base);
        if (col < m) es[col] = sorted2[off + base + col];
        __syncthreads();

        int j = 0;
        for (; j + 1 < m; j += 2) {
            const int2 e0 = es[j];
            const int2 e1 = es[j + 1];
            float v0 = bc + bf16_to_f32(P[(size_t)e0.y * D_OUT + col]);
            float v1 = bc + bf16_to_f32(P[(size_t)e1.y * D_OUT + col]);
            const float4* x0 = &Xe4[(size_t)e0.x * 8];
            const float4* x1 = &Xe4[(size_t)e1.x * 8];
            #pragma unroll
            for (int kk = 0; kk < 8; ++kk) {
                const float4 a0 = x0[kk], a1 = x1[kk];
                v0 += a0.x * we[4*kk+0] + a0.y * we[4*kk+1] + a0.z * we[4*kk+2] + a0.w * we[4*kk+3];
                v1 += a1.x * we[4*kk+0] + a1.y * we[4*kk+1] + a1.z * we[4*kk+2] + a1.w * we[4*kk+3];
            }
            acc += fmaxf(v0, 0.f) + fmaxf(v1, 0.f);
        }
        if (j < m) {
            const int2 e0 = es[j];
            float v0 = bc + bf16_to_f32(P[(size_t)e0.y * D_OUT + col]);
            const float4* x0 = &Xe4[(size_t)e0.x * 8];
            #pragma unroll
            for (int kk = 0; kk < 8; ++kk) {
                const float4 a0 = x0[kk];
                v0 += a0.x * we[4*kk+0] + a0.y * we[4*kk+1] + a0.z * we[4*kk+2] + a0.w * we[4*kk+3];
            }
            acc += fmaxf(v0, 0.f);
        }
        __syncthreads();
    }
    H[(size_t)n * D_OUT + col] += acc;
}

// ---------------------------------------------------------------------------
// Fallback: atomic scatter with bf16 P (if sort workspace doesn't fit).
// ---------------------------------------------------------------------------
__global__ __launch_bounds__(256) void edge_scatter(
    const unsigned short* __restrict__ P, const float* __restrict__ Xe,
    const float* __restrict__ We, const float* __restrict__ b,
    const int* __restrict__ src, const int* __restrict__ dst,
    float* __restrict__ H, int E)
{
    const int tid = threadIdx.x;
    const int col = tid & 127;
    const int sub = tid >> 7;
    float we[D_EDGE];
    #pragma unroll
    for (int k = 0; k < D_EDGE; ++k) we[k] = We[k * D_OUT + col];
    const float bc = b[col];
    const float4* Xe4 = (const float4*)Xe;
    const int slot = blockIdx.x * 2 + sub;
    const int nslots = gridDim.x * 2;
    for (int e = slot; e < E; e += nslots) {
        const int s = src[e];
        const int dt = dst[e];
        float acc = bc + bf16_to_f32(P[(size_t)s * D_OUT + col]);
        #pragma unroll
        for (int kk = 0; kk < 8; ++kk) {
            const float4 xv = Xe4[(size_t)e * 8 + kk];
            acc += xv.x * we[4 * kk + 0] + xv.y * we[4 * kk + 1]
                 + xv.z * we[4 * kk + 2] + xv.w * we[4 * kk + 3];
        }
        acc = fmaxf(acc, 0.f);
        unsafeAtomicAdd(&H[(size_t)dt * D_OUT + col], acc);
    }
}

extern "C" void kernel_launch(void* const* d_in, const int* in_sizes, int n_in,
                              void* d_out, int out_size, void* d_ws, size_t ws_size,
                              hipStream_t stream)
{
    const float* X_user    = (const float*)d_in[0];
    const float* X_item    = (const float*)d_in[1];
    const float* Xe_ui     = (const float*)d_in[2];
    const float* Xe_iu     = (const float*)d_in[3];
    const float* W_src_ui  = (const float*)d_in[4];
    const float* W_edge_ui = (const float*)d_in[5];
    const float* b_ui      = (const float*)d_in[6];
    const float* W_src_iu  = (const float*)d_in[7];
    const float* W_edge_iu = (const float*)d_in[8];
    const float* b_iu      = (const float*)d_in[9];
    const float* Wl_user   = (const float*)d_in[10];
    const float* bl_user   = (const float*)d_in[11];
    const float* Wl_item   = (const float*)d_in[12];
    const float* bl_item   = (const float*)d_in[13];
    const int*   src_ui    = (const int*)d_in[14];
    const int*   dst_ui    = (const int*)d_in[15];
    const int*   src_iu    = (const int*)d_in[16];
    const int*   dst_iu    = (const int*)d_in[17];

    const int NU = in_sizes[0] / D_IN;
    const int NI = in_sizes[1] / D_IN;
    const int E  = in_sizes[14];

    float* H_user = (float*)d_out;
    float* H_item = H_user + (size_t)NU * D_OUT;

    // ---- workspace layout ----
    char*  base = (char*)d_ws;
    size_t wo   = 0;
    auto take = [&](size_t bytes) -> void* {
        void* p = base + wo;
        wo = (wo + bytes + 255) & ~(size_t)255;
        return p;
    };
    unsigned short* P_user = (unsigned short*)take((size_t)NU * D_OUT * 2);
    unsigned short* P_item = (unsigned short*)take((size_t)NI * D_OUT * 2);
    short* Wt_su = (short*)take((size_t)D_IN * D_OUT * 2);  // W_src_ui^T bf16
    short* Wt_lu = (short*)take((size_t)D_IN * D_OUT * 2);  // Wl_user^T
    short* Wt_si = (short*)take((size_t)D_IN * D_OUT * 2);  // W_src_iu^T
    short* Wt_li = (short*)take((size_t)D_IN * D_OUT * 2);  // Wl_item^T
    const size_t need_P = wo;
    int2* sorted_ui = (int2*)take((size_t)E * 8);
    int2* sorted_iu = (int2*)take((size_t)E * 8);
    int*  offs_i    = (int*)take(((size_t)NI + 1) * 4);  // dst of ui = items
    int*  offs_u    = (int*)take(((size_t)NU + 1) * 4);  // dst of iu = users
    int*  cnt_i     = (int*)take(((size_t)NI + (size_t)NU) * 4);
    int*  cnt_u     = cnt_i + NI;
    const int nch_i = (NI + 255) / 256;
    const int nch_u = (NU + 255) / 256;
    int*  bsum_i    = (int*)take((size_t)nch_i * 4);
    int*  bsum_u    = (int*)take((size_t)nch_u * 4);
    const size_t need_sort = wo;

    const int ngrid_u = (NU + 63) / 64;
    const int ngrid_i = (NI + 63) / 64;

    // Weight prep (tiny)
    prep_wt<<<1, 256, 0, stream>>>(W_src_ui, Wt_su);
    prep_wt<<<1, 256, 0, stream>>>(Wl_user,  Wt_lu);
    prep_wt<<<1, 256, 0, stream>>>(W_src_iu, Wt_si);
    prep_wt<<<1, 256, 0, stream>>>(Wl_item,  Wt_li);

    // Node transforms (MFMA): P + self-loop init of H
    node_mfma<<<ngrid_u, 256, 0, stream>>>(
        X_user, Wt_su, Wt_lu, bl_user, P_user, H_user, NU);
    node_mfma<<<ngrid_i, 256, 0, stream>>>(
        X_item, Wt_si, Wt_li, bl_item, P_item, H_item, NI);

    if (ws_size >= need_sort && nch_i <= 512 && nch_u <= 512) {
        // ---- counting sort + atomic-free gather ----
        hipMemsetAsync(cnt_i, 0, ((size_t)NI + (size_t)NU) * 4, stream);
        hist2<<<2048, 256, 0, stream>>>(dst_ui, dst_iu, cnt_i, cnt_u, E);

        scan1<<<nch_i, 256, 0, stream>>>(cnt_i, offs_i, bsum_i, NI);
        scan2<<<1, 512, 0, stream>>>(bsum_i, offs_i, NI, nch_i, E);
        scan3<<<nch_i, 256, 0, stream>>>(offs_i, bsum_i, NI);

        scan1<<<nch_u, 256, 0, stream>>>(cnt_u, offs_u, bsum_u, NU);
        scan2<<<1, 512, 0, stream>>>(bsum_u, offs_u, NU, nch_u, E);
        scan3<<<nch_u, 256, 0, stream>>>(offs_u, bsum_u, NU);

        scatter_sort<<<2048, 256, 0, stream>>>(dst_ui, src_ui, offs_i, cnt_i, sorted_ui, E);
        scatter_sort<<<2048, 256, 0, stream>>>(dst_iu, src_iu, offs_u, cnt_u, sorted_iu, E);

        aggregate<<<NI, 128, 0, stream>>>(
            P_user, Xe_ui, W_edge_ui, b_ui, sorted_ui, offs_i, H_item, NI);
        aggregate<<<NU, 128, 0, stream>>>(
            P_item, Xe_iu, W_edge_iu, b_iu, sorted_iu, offs_u, H_user, NU);
    } else {
        // ---- fallback: atomic scatter ----
        edge_scatter<<<8192, 256, 0, stream>>>(
            P_user, Xe_ui, W_edge_ui, b_ui, src_ui, dst_ui, H_item, E);
        edge_scatter<<<8192, 256, 0, stream>>>(
            P_item, Xe_iu, W_edge_iu, b_iu, src_iu, dst_iu, H_user, E);
    }
}